// Round 16
// baseline (78.093 us; speedup 1.0000x reference)
//
#include <hip/hip_runtime.h>
#include <math.h>

#define B_   16
#define C_   256
#define N_   1024
#define NH   4
#define HD   64
#define EPSV 1e-5f
#define LOG2E 1.44269504088896f

typedef __attribute__((ext_vector_type(8)))  short  bf16x8;
typedef __attribute__((ext_vector_type(8)))  ushort us8;
typedef __attribute__((ext_vector_type(4)))  float  f32x4;
typedef __attribute__((ext_vector_type(16))) float  f32x16;

__device__ inline ushort f2bf(float f) {
    union { float f; unsigned u; } v; v.f = f;
    unsigned r = v.u + 0x7fffu + ((v.u >> 16) & 1u);
    return (ushort)(r >> 16);
}

__device__ inline unsigned cvtpk(float lo, float hi) {
    unsigned r;
    asm("v_cvt_pk_bf16_f32 %0, %1, %2" : "=v"(r) : "v"(lo), "v"(hi));
    return r;
}

// exact 2^x via HW transcendental
__device__ inline float fexp2(float x) {
    float r;
    asm("v_exp_f32 %0, %1" : "=v"(r) : "v"(x));
    return r;
}

// v_permlane32_swap_b32 d, s: swaps UPPER 32 lanes of d with LOWER 32 lanes of s.
#if __has_builtin(__builtin_amdgcn_permlane32_swap)
__device__ inline void plswap_pair(unsigned &d, unsigned &s) {
    auto r = __builtin_amdgcn_permlane32_swap(d, s, false, false);
    d = r[0]; s = r[1];
}
__device__ inline void plswap_same(unsigned x, unsigned &lo, unsigned &hi) {
    auto r = __builtin_amdgcn_permlane32_swap(x, x, false, false);
    lo = r[0]; hi = r[1];
}
#else
__device__ inline void plswap_pair(unsigned &d, unsigned &s) {
    asm("v_permlane32_swap_b32 %0, %1" : "+v"(d), "+v"(s));
}
__device__ inline void plswap_same(unsigned x, unsigned &lo, unsigned &hi) {
    asm("v_mov_b32 %0, %2\n\t"
        "v_mov_b32 %1, %2\n\t"
        "v_permlane32_swap_b32 %0, %1"
        : "=&v"(lo), "=&v"(hi) : "v"(x));
}
#endif

__device__ inline float sumhalves(float x) {
    union { float f; unsigned u; } a; a.f = x;
    unsigned lo, hi;
    plswap_same(a.u, lo, hi);
    union { unsigned u; float f; } L, H; L.u = lo; H.u = hi;
    return L.f + H.f;
}

#define GLOAD16(gsrc, ldst) \
  __builtin_amdgcn_global_load_lds((const __attribute__((address_space(1))) unsigned int*)(gsrc), \
                                   (__attribute__((address_space(3))) unsigned int*)(ldst), 16, 0, 0)

// ---------------- Kernel 0: weight prep (f32 -> bf16) ----------------
__global__ __launch_bounds__(256) void prep_w(const float* __restrict__ qw,
                                              const float* __restrict__ pw,
                                              ushort* __restrict__ wq,
                                              ushort* __restrict__ wp) {
    int i = blockIdx.x * 256 + threadIdx.x;
    int T = gridDim.x * 256;
    for (int t = i; t < 49152; t += T) {
        float4 v = ((const float4*)qw)[t];
        ushort4 o; o.x = f2bf(v.x); o.y = f2bf(v.y); o.z = f2bf(v.z); o.w = f2bf(v.w);
        ((ushort4*)wq)[t] = o;
    }
    for (int t = i; t < 16384; t += T) {
        float4 v = ((const float4*)pw)[t];
        ushort4 o; o.x = f2bf(v.x); o.y = f2bf(v.y); o.z = f2bf(v.z); o.w = f2bf(v.w);
        ((ushort4*)wp)[t] = o;
    }
}

// ---------------- Kernel 1: GroupNorm -> bf16 transposed [b][n][c] ----------------
__global__ __launch_bounds__(256) void gn_kernel(const float* __restrict__ x,
                                                 const float* __restrict__ gw,
                                                 const float* __restrict__ gb,
                                                 ushort* __restrict__ xnt) {
    __shared__ ushort Ls[16][1028];
    __shared__ float redS[2][4], redQ[2][4], stats[2][2];
    int b = blockIdx.x >> 4, gp = blockIdx.x & 15;
    const float4* px4 = (const float4*)(x + ((size_t)b * C_ + gp * 16) * N_);
    int tid = threadIdx.x;

    float4 vals[16];
    float s0 = 0.f, q0 = 0.f, s1 = 0.f, q1 = 0.f;
    #pragma unroll
    for (int p = 0; p < 16; ++p) {
        float4 v = px4[p * 256 + tid];
        vals[p] = v;
        float ss = v.x + v.y + v.z + v.w;
        float qq = v.x * v.x + v.y * v.y + v.z * v.z + v.w * v.w;
        if (p < 8) { s0 += ss; q0 += qq; } else { s1 += ss; q1 += qq; }
    }
    #pragma unroll
    for (int off = 32; off; off >>= 1) {
        s0 += __shfl_down(s0, off); q0 += __shfl_down(q0, off);
        s1 += __shfl_down(s1, off); q1 += __shfl_down(q1, off);
    }
    int w = tid >> 6, lane = tid & 63;
    if (lane == 0) { redS[0][w] = s0; redQ[0][w] = q0; redS[1][w] = s1; redQ[1][w] = q1; }
    __syncthreads();
    if (tid < 2) {
        float S = redS[tid][0] + redS[tid][1] + redS[tid][2] + redS[tid][3];
        float Q = redQ[tid][0] + redQ[tid][1] + redQ[tid][2] + redQ[tid][3];
        float mean = S * (1.f / 8192.f);
        float var  = Q * (1.f / 8192.f) - mean * mean;
        stats[tid][0] = mean;
        stats[tid][1] = rsqrtf(var + EPSV);
    }
    __syncthreads();
    #pragma unroll
    for (int p = 0; p < 16; ++p) {
        int grp = p >> 3;
        int ch = gp * 16 + p;
        float ga = gw[ch] * stats[grp][1];
        float be = gb[ch] - stats[grp][0] * ga;
        float4 v = vals[p];
        ushort4 o;
        o.x = f2bf(v.x * ga + be); o.y = f2bf(v.y * ga + be);
        o.z = f2bf(v.z * ga + be); o.w = f2bf(v.w * ga + be);
        *(ushort4*)&Ls[p][tid * 4] = o;
    }
    __syncthreads();
    #pragma unroll
    for (int it = 0; it < 4; ++it) {
        int n = it * 256 + tid;
        us8 a, b2;
        #pragma unroll
        for (int c = 0; c < 8; ++c) { a[c] = Ls[c][n]; b2[c] = Ls[8 + c][n]; }
        ushort* dst = xnt + ((size_t)b * N_ + n) * C_ + gp * 16;
        *(us8*)dst = a;
        *(us8*)(dst + 8) = b2;
    }
}

// ---------------- Kernel 2: QKV GEMM (bf16 MFMA) ----------------
__global__ __launch_bounds__(256) void qkv_gemm(const ushort* __restrict__ wq,
                                                const ushort* __restrict__ xnt,
                                                const float* __restrict__ bias,
                                                ushort* __restrict__ Qd,
                                                ushort* __restrict__ Kd,
                                                ushort* __restrict__ Vd) {
    __shared__ union {
        struct { ushort As[64][72]; ushort Bs[128][72]; } s;
        ushort Ts[128][72];
    } u;
    int b = blockIdx.z, mt = blockIdx.y, n0 = blockIdx.x * 128;
    int s_ = mt >> 2, h = mt & 3;
    const ushort* Bsrc = xnt + (size_t)b * N_ * C_;
    int tid = threadIdx.x;
    int w = tid >> 6, lane = tid & 63;
    int g = lane >> 4, r16 = lane & 15;
    int wm = w >> 1, wn = w & 1;

    f32x4 acc[2][4];
    #pragma unroll
    for (int mf = 0; mf < 2; ++mf)
        #pragma unroll
        for (int nf = 0; nf < 4; ++nf) acc[mf][nf] = (f32x4){0.f, 0.f, 0.f, 0.f};

    for (int k0 = 0; k0 < 256; k0 += 64) {
        __syncthreads();
        #pragma unroll
        for (int it = 0; it < 2; ++it) {
            int t = it * 256 + tid, r = t >> 3, c = t & 7;
            *(us8*)&u.s.As[r][c * 8] = *(const us8*)(wq + (size_t)(mt * 64 + r) * 256 + k0 + c * 8);
        }
        #pragma unroll
        for (int it = 0; it < 4; ++it) {
            int t = it * 256 + tid, r = t >> 3, c = t & 7;
            *(us8*)&u.s.Bs[r][c * 8] = *(const us8*)(Bsrc + (size_t)(n0 + r) * 256 + k0 + c * 8);
        }
        __syncthreads();
        bf16x8 aA[2][2], bB[4][2];
        #pragma unroll
        for (int mf = 0; mf < 2; ++mf)
            #pragma unroll
            for (int ks = 0; ks < 2; ++ks)
                aA[mf][ks] = *(const bf16x8*)&u.s.As[wm * 32 + mf * 16 + r16][ks * 32 + g * 8];
        #pragma unroll
        for (int nf = 0; nf < 4; ++nf)
            #pragma unroll
            for (int ks = 0; ks < 2; ++ks)
                bB[nf][ks] = *(const bf16x8*)&u.s.Bs[wn * 64 + nf * 16 + r16][ks * 32 + g * 8];
        #pragma unroll
        for (int ks = 0; ks < 2; ++ks)
            #pragma unroll
            for (int mf = 0; mf < 2; ++mf)
                #pragma unroll
                for (int nf = 0; nf < 4; ++nf)
                    acc[mf][nf] = __builtin_amdgcn_mfma_f32_16x16x32_bf16(aA[mf][ks], bB[nf][ks], acc[mf][nf], 0, 0, 0);
    }
    __syncthreads();

    float scale = (s_ == 0) ? 0.125f * LOG2E : 1.f;
    float bfr[2][4];
    #pragma unroll
    for (int mf = 0; mf < 2; ++mf)
        #pragma unroll
        for (int reg = 0; reg < 4; ++reg)
            bfr[mf][reg] = bias[mt * 64 + wm * 32 + mf * 16 + g * 4 + reg];

    if (s_ < 2) {
        #pragma unroll
        for (int mf = 0; mf < 2; ++mf)
            #pragma unroll
            for (int nf = 0; nf < 4; ++nf)
                #pragma unroll
                for (int reg = 0; reg < 4; ++reg)
                    u.Ts[wn * 64 + nf * 16 + r16][wm * 32 + mf * 16 + g * 4 + reg] =
                        f2bf((acc[mf][nf][reg] + bfr[mf][reg]) * scale);
        __syncthreads();
        ushort* dst = (s_ == 0 ? Qd : Kd) + ((size_t)(b * NH + h) * N_ + n0) * HD;
        #pragma unroll
        for (int it = 0; it < 4; ++it) {
            int t = it * 256 + tid, r = t >> 3, c = t & 7;
            *(us8*)(dst + (size_t)r * HD + c * 8) = *(const us8*)&u.Ts[r][c * 8];
        }
    } else {
        #pragma unroll
        for (int mf = 0; mf < 2; ++mf)
            #pragma unroll
            for (int nf = 0; nf < 4; ++nf)
                #pragma unroll
                for (int reg = 0; reg < 4; ++reg) {
                    int d = wm * 32 + mf * 16 + g * 4 + reg;
                    int n = n0 + wn * 64 + nf * 16 + r16;
                    Vd[((size_t)(b * NH + h) * HD + d) * N_ + n] = f2bf(acc[mf][nf][reg] + bfr[mf][reg]);
                }
    }
}

// ---------------- Kernel 3: MFMA flash attention v6 (fragment-major LDS) ----------------
// grid 1024: bh = n&63, qt = n>>6. 128 threads = 2 waves x 32 q.
// K/V tiles stored in LDS in CONSUMPTION ORDER: 8 regions x 1KB per tile,
// region = one (t,c) [K] or (kt,dt) [V] fragment read; slot = lane*16B.
// Fragment reads are base+lane*16 (linear, ZERO bank conflicts, zero addr VALU);
// GLOAD16 source addresses carry the layout permutation (rule #21).
// No-max softmax in exp2 domain; permlane32_swap pair-exchange for P.
#define KT 64
__global__ __launch_bounds__(128) void attn_mfma(const ushort* __restrict__ Qd,
                                                 const ushort* __restrict__ Kd,
                                                 const ushort* __restrict__ Vd,
                                                 ushort* __restrict__ att) {
    __shared__ union {
        struct { ushort Kb[2][4096]; ushort Vb[2][4096]; } s;   // 16 KB + 16 KB
        float Op[64][68];
    } u;
    __shared__ float Lsh[64];
    int nblk = blockIdx.x;
    int bh = nblk & 63, qt = nblk >> 6;
    int b = bh >> 2, head = bh & 3;
    int i0 = qt * 64;
    const ushort* qp = Qd + (size_t)bh * N_ * HD;
    const ushort* kp = Kd + (size_t)bh * N_ * HD;
    const ushort* vp = Vd + (size_t)bh * HD * N_;

    int tid = threadIdx.x;
    int w = tid >> 6, lane = tid & 63;
    int hl = lane >> 5, r32 = lane & 31;

    // per-lane staging source offsets (elements), regions w*4+p
    int kgl[4], vgl[4];
    #pragma unroll
    for (int p = 0; p < 4; ++p) {
        int rk = w * 4 + p, t = rk >> 2, c = rk & 3;
        kgl[p] = (t * 32 + r32) * HD + c * 16 + hl * 8;
        int rv = w * 4 + p, kt = rv >> 1, dt = rv & 1;
        vgl[p] = (dt * 32 + r32) * N_ + kt * 16 + hl * 8;
    }
    // per-lane fragment read bases (slot = lane*16B = lane*8 ushorts)
    const ushort* kbL = &u.s.Kb[0][0] + lane * 8;
    const ushort* vbL = &u.s.Vb[0][0] + lane * 8;

    // Q B-fragments: q_glob = i0 + w*32 + r32
    bf16x8 aQ[4];
    {
        const ushort* qrow = qp + (size_t)(i0 + w * 32 + r32) * HD;
        #pragma unroll
        for (int c = 0; c < 4; ++c)
            aQ[c] = *(const bf16x8*)(qrow + c * 16 + hl * 8);
    }

    float l = 0.f;
    f32x16 oacc[2];
    #pragma unroll
    for (int dt = 0; dt < 2; ++dt)
        #pragma unroll
        for (int i = 0; i < 16; ++i) oacc[dt][i] = 0.f;

    // prologue: stage tile 0 -> buf 0
    #pragma unroll
    for (int p = 0; p < 4; ++p) {
        GLOAD16(kp + kgl[p], &u.s.Kb[0][(w * 4 + p) * 512]);
        GLOAD16(vp + vgl[p], &u.s.Vb[0][(w * 4 + p) * 512]);
    }
    __syncthreads();

    auto body = [&](int cb, int it) {
        if (it < 15) {   // async prefetch next tile into the other buffer
            const ushort* kpi = kp + (it + 1) * (64 * HD);
            const ushort* vpi = vp + (it + 1) * 64;
            #pragma unroll
            for (int p = 0; p < 4; ++p) {
                GLOAD16(kpi + kgl[p], &u.s.Kb[cb ^ 1][(w * 4 + p) * 512]);
                GLOAD16(vpi + vgl[p], &u.s.Vb[cb ^ 1][(w * 4 + p) * 512]);
            }
        }

        // ---- QK^T swapped (32x32x16): linear region reads ----
        f32x16 sacc[2];
        #pragma unroll
        for (int t = 0; t < 2; ++t)
            #pragma unroll
            for (int i = 0; i < 16; ++i) sacc[t][i] = 0.f;
        __builtin_amdgcn_s_setprio(1);
        #pragma unroll
        for (int t = 0; t < 2; ++t)
            #pragma unroll
            for (int c = 0; c < 4; ++c) {
                bf16x8 aK = *(const bf16x8*)(kbL + cb * 4096 + (t * 4 + c) * 512);
                sacc[t] = __builtin_amdgcn_mfma_f32_32x32x16_bf16(aK, aQ[c], sacc[t], 0, 0, 0);
            }
        __builtin_amdgcn_s_setprio(0);

        // ---- no-max softmax: P = exp2(S) ----
        float p0[16], p1[16];
        #pragma unroll
        for (int i = 0; i < 16; ++i) p0[i] = fexp2(sacc[0][i]);
        #pragma unroll
        for (int i = 0; i < 16; ++i) p1[i] = fexp2(sacc[1][i]);
        float s8[8];
        #pragma unroll
        for (int i = 0; i < 8; ++i) s8[i] = (p0[i] + p0[i + 8]) + (p1[i] + p1[i + 8]);
        float s4a = s8[0] + s8[4], s4b = s8[1] + s8[5], s4c = s8[2] + s8[6], s4d = s8[3] + s8[7];
        float sum = (s4a + s4b) + (s4c + s4d);
        sum = sumhalves(sum);
        l += sum;

        // ---- pack P; permlane32_swap pair-exchange -> A-fragments ----
        unsigned pk0[4][2], pk1[4][2];
        #pragma unroll
        for (int R = 0; R < 4; ++R) {
            pk0[R][0] = cvtpk(p0[R * 4 + 0], p0[R * 4 + 1]);
            pk0[R][1] = cvtpk(p0[R * 4 + 2], p0[R * 4 + 3]);
            pk1[R][0] = cvtpk(p1[R * 4 + 0], p1[R * 4 + 1]);
            pk1[R][1] = cvtpk(p1[R * 4 + 2], p1[R * 4 + 3]);
        }
        unsigned apk[4][4];
        #pragma unroll
        for (int t = 0; t < 2; ++t)
            #pragma unroll
            for (int s2 = 0; s2 < 2; ++s2) {
                int kt = 2 * t + s2;
                unsigned w0 = t ? pk1[2 * s2][0]     : pk0[2 * s2][0];
                unsigned w1 = t ? pk1[2 * s2][1]     : pk0[2 * s2][1];
                unsigned w2 = t ? pk1[2 * s2 + 1][0] : pk0[2 * s2 + 1][0];
                unsigned w3 = t ? pk1[2 * s2 + 1][1] : pk0[2 * s2 + 1][1];
                plswap_pair(w0, w2);
                plswap_pair(w1, w3);
                apk[kt][0] = w0; apk[kt][1] = w1;
                apk[kt][2] = w2; apk[kt][3] = w3;
            }

        // ---- PV (32x32x16): linear region reads ----
        __builtin_amdgcn_s_setprio(1);
        #pragma unroll
        for (int kt = 0; kt < 4; ++kt) {
            union { unsigned uu[4]; bf16x8 v; } ap;
            ap.uu[0] = apk[kt][0]; ap.uu[1] = apk[kt][1];
            ap.uu[2] = apk[kt][2]; ap.uu[3] = apk[kt][3];
            #pragma unroll
            for (int dt = 0; dt < 2; ++dt) {
                bf16x8 bV = *(const bf16x8*)(vbL + cb * 4096 + (kt * 2 + dt) * 512);
                oacc[dt] = __builtin_amdgcn_mfma_f32_32x32x16_bf16(ap.v, bV, oacc[dt], 0, 0, 0);
            }
        }
        __builtin_amdgcn_s_setprio(0);

        __syncthreads();   // drains prefetch vmcnt + all waves done with buf[cb]
    };

    #pragma unroll 1
    for (int ii = 0; ii < 8; ++ii) {
        body(0, 2 * ii);
        body(1, 2 * ii + 1);
    }

    // ---- epilogue: raw O -> LDS transpose, normalize on store ----
    if (hl == 0) Lsh[w * 32 + r32] = 1.f / l;
    #pragma unroll
    for (int dt = 0; dt < 2; ++dt)
        #pragma unroll
        for (int reg = 0; reg < 16; ++reg)
            u.Op[w * 32 + (reg & 3) + 8 * (reg >> 2) + 4 * hl][dt * 32 + r32] = oacc[dt][reg];
    __syncthreads();

    #pragma unroll
    for (int it = 0; it < 4; ++it) {
        int t = it * 128 + tid;
        int r = t >> 3, c = t & 7;
        float linv = Lsh[r];
        f32x4 v0 = *(const f32x4*)&u.Op[r][c * 8];
        f32x4 v1 = *(const f32x4*)&u.Op[r][c * 8 + 4];
        union { unsigned uu[4]; us8 v; } ov;
        ov.uu[0] = cvtpk(v0[0] * linv, v0[1] * linv);
        ov.uu[1] = cvtpk(v0[2] * linv, v0[3] * linv);
        ov.uu[2] = cvtpk(v1[0] * linv, v1[1] * linv);
        ov.uu[3] = cvtpk(v1[2] * linv, v1[3] * linv);
        *(us8*)(att + ((size_t)b * N_ + i0 + r) * C_ + head * HD + c * 8) = ov.v;
    }
}

// ---------------- Kernel 4: proj GEMM (bf16 MFMA) + bias + residual ----------------
__global__ __launch_bounds__(256) void proj_gemm(const ushort* __restrict__ wp,
                                                 const ushort* __restrict__ att,
                                                 const float* __restrict__ bias,
                                                 const float* __restrict__ x,
                                                 float* __restrict__ out) {
    __shared__ struct { ushort As[64][72]; ushort Bs[128][72]; } s;
    int b = blockIdx.z, m0 = blockIdx.y * 64, n0 = blockIdx.x * 128;
    const ushort* Bsrc = att + (size_t)b * N_ * C_;
    int tid = threadIdx.x;
    int w = tid >> 6, lane = tid & 63;
    int g = lane >> 4, r16 = lane & 15;
    int wm = w >> 1, wn = w & 1;

    f32x4 acc[2][4];
    #pragma unroll
    for (int mf = 0; mf < 2; ++mf)
        #pragma unroll
        for (int nf = 0; nf < 4; ++nf) acc[mf][nf] = (f32x4){0.f, 0.f, 0.f, 0.f};

    for (int k0 = 0; k0 < 256; k0 += 64) {
        __syncthreads();
        #pragma unroll
        for (int it = 0; it < 2; ++it) {
            int t = it * 256 + tid, r = t >> 3, c = t & 7;
            *(us8*)&s.As[r][c * 8] = *(const us8*)(wp + (size_t)(m0 + r) * 256 + k0 + c * 8);
        }
        #pragma unroll
        for (int it = 0; it < 4; ++it) {
            int t = it * 256 + tid, r = t >> 3, c = t & 7;
            *(us8*)&s.Bs[r][c * 8] = *(const us8*)(Bsrc + (size_t)(n0 + r) * 256 + k0 + c * 8);
        }
        __syncthreads();
        bf16x8 aA[2][2], bB[4][2];
        #pragma unroll
        for (int mf = 0; mf < 2; ++mf)
            #pragma unroll
            for (int ks = 0; ks < 2; ++ks)
                aA[mf][ks] = *(const bf16x8*)&s.As[wm * 32 + mf * 16 + r16][ks * 32 + g * 8];
        #pragma unroll
        for (int nf = 0; nf < 4; ++nf)
            #pragma unroll
            for (int ks = 0; ks < 2; ++ks)
                bB[nf][ks] = *(const bf16x8*)&s.Bs[wn * 64 + nf * 16 + r16][ks * 32 + g * 8];
        #pragma unroll
        for (int ks = 0; ks < 2; ++ks)
            #pragma unroll
            for (int mf = 0; mf < 2; ++mf)
                #pragma unroll
                for (int nf = 0; nf < 4; ++nf)
                    acc[mf][nf] = __builtin_amdgcn_mfma_f32_16x16x32_bf16(aA[mf][ks], bB[nf][ks], acc[mf][nf], 0, 0, 0);
    }

    #pragma unroll
    for (int mf = 0; mf < 2; ++mf) {
        #pragma unroll
        for (int reg = 0; reg < 4; ++reg) {
            int c_ = m0 + wm * 32 + mf * 16 + g * 4 + reg;
            float bi = bias[c_];
            #pragma unroll
            for (int nf = 0; nf < 4; ++nf) {
                int n = n0 + wn * 64 + nf * 16 + r16;
                size_t o = ((size_t)b * C_ + c_) * N_ + n;
                out[o] = acc[mf][nf][reg] + bi + x[o];
            }
        }
    }
}

extern "C" void kernel_launch(void* const* d_in, const int* in_sizes, int n_in,
                              void* d_out, int out_size, void* d_ws, size_t ws_size,
                              hipStream_t stream) {
    const float* x      = (const float*)d_in[0];
    const float* gn_w   = (const float*)d_in[1];
    const float* gn_b   = (const float*)d_in[2];
    const float* qkv_w  = (const float*)d_in[3];
    const float* qkv_b  = (const float*)d_in[4];
    const float* proj_w = (const float*)d_in[5];
    const float* proj_b = (const float*)d_in[6];
    float* out = (float*)d_out;

    char* ws = (char*)d_ws;
    ushort* wq_bf = (ushort*)(ws);                               // 384 KB
    ushort* wp_bf = (ushort*)(ws + 393216);                      // 128 KB
    ushort* xnt   = (ushort*)(ws + (1u << 20));                  // 8 MB  [b][n][c]
    ushort* Qd    = (ushort*)(ws + (size_t)16 * 1024 * 1024);    // 8 MB  [b][h][n][d]
    ushort* Kd    = (ushort*)(ws + (size_t)24 * 1024 * 1024);    // 8 MB  [b][h][n][d]
    ushort* Vd    = (ushort*)(ws + (size_t)32 * 1024 * 1024);    // 8 MB  [b][h][d][n]
    ushort* att_t = (ushort*)(ws + (size_t)40 * 1024 * 1024);    // 8 MB  [b][n][c]

    prep_w<<<dim3(256), dim3(256), 0, stream>>>(qkv_w, proj_w, wq_bf, wp_bf);
    gn_kernel<<<dim3(B_ * 16), dim3(256), 0, stream>>>(x, gn_w, gn_b, xnt);
    qkv_gemm<<<dim3(8, 12, B_), dim3(256), 0, stream>>>(wq_bf, xnt, qkv_b, Qd, Kd, Vd);
    attn_mfma<<<dim3(1024), dim3(128), 0, stream>>>(Qd, Kd, Vd, att_t);
    proj_gemm<<<dim3(8, 4, B_), dim3(256), 0, stream>>>(wp_bf, att_t, proj_b, x, out);
}

// Round 17
// 75.018 us; speedup vs baseline: 1.0410x; 1.0410x over previous
//
#include <hip/hip_runtime.h>
#include <math.h>

#define B_   16
#define C_   256
#define N_   1024
#define NH   4
#define HD   64
#define EPSV 1e-5f
#define LOG2E 1.44269504088896f

typedef __attribute__((ext_vector_type(8)))  short  bf16x8;
typedef __attribute__((ext_vector_type(8)))  ushort us8;
typedef __attribute__((ext_vector_type(4)))  float  f32x4;
typedef __attribute__((ext_vector_type(16))) float  f32x16;

__device__ inline ushort f2bf(float f) {
    union { float f; unsigned u; } v; v.f = f;
    unsigned r = v.u + 0x7fffu + ((v.u >> 16) & 1u);
    return (ushort)(r >> 16);
}

__device__ inline unsigned cvtpk(float lo, float hi) {
    unsigned r;
    asm("v_cvt_pk_bf16_f32 %0, %1, %2" : "=v"(r) : "v"(lo), "v"(hi));
    return r;
}

// exact 2^x via HW transcendental
__device__ inline float fexp2(float x) {
    float r;
    asm("v_exp_f32 %0, %1" : "=v"(r) : "v"(x));
    return r;
}

// v_permlane32_swap_b32 d, s: swaps UPPER 32 lanes of d with LOWER 32 lanes of s.
#if __has_builtin(__builtin_amdgcn_permlane32_swap)
__device__ inline void plswap_pair(unsigned &d, unsigned &s) {
    auto r = __builtin_amdgcn_permlane32_swap(d, s, false, false);
    d = r[0]; s = r[1];
}
__device__ inline void plswap_same(unsigned x, unsigned &lo, unsigned &hi) {
    auto r = __builtin_amdgcn_permlane32_swap(x, x, false, false);
    lo = r[0]; hi = r[1];
}
#else
__device__ inline void plswap_pair(unsigned &d, unsigned &s) {
    asm("v_permlane32_swap_b32 %0, %1" : "+v"(d), "+v"(s));
}
__device__ inline void plswap_same(unsigned x, unsigned &lo, unsigned &hi) {
    asm("v_mov_b32 %0, %2\n\t"
        "v_mov_b32 %1, %2\n\t"
        "v_permlane32_swap_b32 %0, %1"
        : "=&v"(lo), "=&v"(hi) : "v"(x));
}
#endif

__device__ inline float sumhalves(float x) {
    union { float f; unsigned u; } a; a.f = x;
    unsigned lo, hi;
    plswap_same(a.u, lo, hi);
    union { unsigned u; float f; } L, H; L.u = lo; H.u = hi;
    return L.f + H.f;
}

#define GLOAD16(gsrc, ldst) \
  __builtin_amdgcn_global_load_lds((const __attribute__((address_space(1))) unsigned int*)(gsrc), \
                                   (__attribute__((address_space(3))) unsigned int*)(ldst), 16, 0, 0)

// ---------------- Kernel 0: weight prep (f32 -> bf16) ----------------
__global__ __launch_bounds__(256) void prep_w(const float* __restrict__ qw,
                                              const float* __restrict__ pw,
                                              ushort* __restrict__ wq,
                                              ushort* __restrict__ wp) {
    int i = blockIdx.x * 256 + threadIdx.x;
    int T = gridDim.x * 256;
    for (int t = i; t < 49152; t += T) {
        float4 v = ((const float4*)qw)[t];
        ushort4 o; o.x = f2bf(v.x); o.y = f2bf(v.y); o.z = f2bf(v.z); o.w = f2bf(v.w);
        ((ushort4*)wq)[t] = o;
    }
    for (int t = i; t < 16384; t += T) {
        float4 v = ((const float4*)pw)[t];
        ushort4 o; o.x = f2bf(v.x); o.y = f2bf(v.y); o.z = f2bf(v.z); o.w = f2bf(v.w);
        ((ushort4*)wp)[t] = o;
    }
}

// ---------------- Kernel 1: GroupNorm -> bf16 transposed [b][n][c] ----------------
__global__ __launch_bounds__(256) void gn_kernel(const float* __restrict__ x,
                                                 const float* __restrict__ gw,
                                                 const float* __restrict__ gb,
                                                 ushort* __restrict__ xnt) {
    __shared__ ushort Ls[16][1028];
    __shared__ float redS[2][4], redQ[2][4], stats[2][2];
    int b = blockIdx.x >> 4, gp = blockIdx.x & 15;
    const float4* px4 = (const float4*)(x + ((size_t)b * C_ + gp * 16) * N_);
    int tid = threadIdx.x;

    float4 vals[16];
    float s0 = 0.f, q0 = 0.f, s1 = 0.f, q1 = 0.f;
    #pragma unroll
    for (int p = 0; p < 16; ++p) {
        float4 v = px4[p * 256 + tid];
        vals[p] = v;
        float ss = v.x + v.y + v.z + v.w;
        float qq = v.x * v.x + v.y * v.y + v.z * v.z + v.w * v.w;
        if (p < 8) { s0 += ss; q0 += qq; } else { s1 += ss; q1 += qq; }
    }
    #pragma unroll
    for (int off = 32; off; off >>= 1) {
        s0 += __shfl_down(s0, off); q0 += __shfl_down(q0, off);
        s1 += __shfl_down(s1, off); q1 += __shfl_down(q1, off);
    }
    int w = tid >> 6, lane = tid & 63;
    if (lane == 0) { redS[0][w] = s0; redQ[0][w] = q0; redS[1][w] = s1; redQ[1][w] = q1; }
    __syncthreads();
    if (tid < 2) {
        float S = redS[tid][0] + redS[tid][1] + redS[tid][2] + redS[tid][3];
        float Q = redQ[tid][0] + redQ[tid][1] + redQ[tid][2] + redQ[tid][3];
        float mean = S * (1.f / 8192.f);
        float var  = Q * (1.f / 8192.f) - mean * mean;
        stats[tid][0] = mean;
        stats[tid][1] = rsqrtf(var + EPSV);
    }
    __syncthreads();
    #pragma unroll
    for (int p = 0; p < 16; ++p) {
        int grp = p >> 3;
        int ch = gp * 16 + p;
        float ga = gw[ch] * stats[grp][1];
        float be = gb[ch] - stats[grp][0] * ga;
        float4 v = vals[p];
        ushort4 o;
        o.x = f2bf(v.x * ga + be); o.y = f2bf(v.y * ga + be);
        o.z = f2bf(v.z * ga + be); o.w = f2bf(v.w * ga + be);
        *(ushort4*)&Ls[p][tid * 4] = o;
    }
    __syncthreads();
    #pragma unroll
    for (int it = 0; it < 4; ++it) {
        int n = it * 256 + tid;
        us8 a, b2;
        #pragma unroll
        for (int c = 0; c < 8; ++c) { a[c] = Ls[c][n]; b2[c] = Ls[8 + c][n]; }
        ushort* dst = xnt + ((size_t)b * N_ + n) * C_ + gp * 16;
        *(us8*)dst = a;
        *(us8*)(dst + 8) = b2;
    }
}

// ---------------- Kernel 2: QKV GEMM (bf16 MFMA) ----------------
__global__ __launch_bounds__(256) void qkv_gemm(const ushort* __restrict__ wq,
                                                const ushort* __restrict__ xnt,
                                                const float* __restrict__ bias,
                                                ushort* __restrict__ Qd,
                                                ushort* __restrict__ Kd,
                                                ushort* __restrict__ Vd) {
    __shared__ union {
        struct { ushort As[64][72]; ushort Bs[128][72]; } s;
        ushort Ts[128][72];
    } u;
    int b = blockIdx.z, mt = blockIdx.y, n0 = blockIdx.x * 128;
    int s_ = mt >> 2, h = mt & 3;
    const ushort* Bsrc = xnt + (size_t)b * N_ * C_;
    int tid = threadIdx.x;
    int w = tid >> 6, lane = tid & 63;
    int g = lane >> 4, r16 = lane & 15;
    int wm = w >> 1, wn = w & 1;

    f32x4 acc[2][4];
    #pragma unroll
    for (int mf = 0; mf < 2; ++mf)
        #pragma unroll
        for (int nf = 0; nf < 4; ++nf) acc[mf][nf] = (f32x4){0.f, 0.f, 0.f, 0.f};

    for (int k0 = 0; k0 < 256; k0 += 64) {
        __syncthreads();
        #pragma unroll
        for (int it = 0; it < 2; ++it) {
            int t = it * 256 + tid, r = t >> 3, c = t & 7;
            *(us8*)&u.s.As[r][c * 8] = *(const us8*)(wq + (size_t)(mt * 64 + r) * 256 + k0 + c * 8);
        }
        #pragma unroll
        for (int it = 0; it < 4; ++it) {
            int t = it * 256 + tid, r = t >> 3, c = t & 7;
            *(us8*)&u.s.Bs[r][c * 8] = *(const us8*)(Bsrc + (size_t)(n0 + r) * 256 + k0 + c * 8);
        }
        __syncthreads();
        bf16x8 aA[2][2], bB[4][2];
        #pragma unroll
        for (int mf = 0; mf < 2; ++mf)
            #pragma unroll
            for (int ks = 0; ks < 2; ++ks)
                aA[mf][ks] = *(const bf16x8*)&u.s.As[wm * 32 + mf * 16 + r16][ks * 32 + g * 8];
        #pragma unroll
        for (int nf = 0; nf < 4; ++nf)
            #pragma unroll
            for (int ks = 0; ks < 2; ++ks)
                bB[nf][ks] = *(const bf16x8*)&u.s.Bs[wn * 64 + nf * 16 + r16][ks * 32 + g * 8];
        #pragma unroll
        for (int ks = 0; ks < 2; ++ks)
            #pragma unroll
            for (int mf = 0; mf < 2; ++mf)
                #pragma unroll
                for (int nf = 0; nf < 4; ++nf)
                    acc[mf][nf] = __builtin_amdgcn_mfma_f32_16x16x32_bf16(aA[mf][ks], bB[nf][ks], acc[mf][nf], 0, 0, 0);
    }
    __syncthreads();

    float scale = (s_ == 0) ? 0.125f * LOG2E : 1.f;
    float bfr[2][4];
    #pragma unroll
    for (int mf = 0; mf < 2; ++mf)
        #pragma unroll
        for (int reg = 0; reg < 4; ++reg)
            bfr[mf][reg] = bias[mt * 64 + wm * 32 + mf * 16 + g * 4 + reg];

    if (s_ < 2) {
        #pragma unroll
        for (int mf = 0; mf < 2; ++mf)
            #pragma unroll
            for (int nf = 0; nf < 4; ++nf)
                #pragma unroll
                for (int reg = 0; reg < 4; ++reg)
                    u.Ts[wn * 64 + nf * 16 + r16][wm * 32 + mf * 16 + g * 4 + reg] =
                        f2bf((acc[mf][nf][reg] + bfr[mf][reg]) * scale);
        __syncthreads();
        ushort* dst = (s_ == 0 ? Qd : Kd) + ((size_t)(b * NH + h) * N_ + n0) * HD;
        #pragma unroll
        for (int it = 0; it < 4; ++it) {
            int t = it * 256 + tid, r = t >> 3, c = t & 7;
            *(us8*)(dst + (size_t)r * HD + c * 8) = *(const us8*)&u.Ts[r][c * 8];
        }
    } else {
        #pragma unroll
        for (int mf = 0; mf < 2; ++mf)
            #pragma unroll
            for (int nf = 0; nf < 4; ++nf)
                #pragma unroll
                for (int reg = 0; reg < 4; ++reg) {
                    int d = wm * 32 + mf * 16 + g * 4 + reg;
                    int n = n0 + wn * 64 + nf * 16 + r16;
                    Vd[((size_t)(b * NH + h) * HD + d) * N_ + n] = f2bf(acc[mf][nf][reg] + bfr[mf][reg]);
                }
    }
}

// ---------------- Kernel 3: MFMA flash attention v7 (KT=32, fragment-major LDS) ----------------
// grid 1024: bh = n&63, qt = n>>6. 128 threads = 2 waves x 32 q.
// KT=32 keys/tile, 32 iters: LDS 17.4 KB -> ~9 blocks/CU (2.25x wave concurrency).
// K tile: 4 regions (c), V tile: 4 regions (kt*2+dt); wave0 stages K, wave1 stages V.
// Fragment reads = base + lane*16B (linear, conflict-free). No-max exp2 softmax.
__global__ __launch_bounds__(128) void attn_mfma(const ushort* __restrict__ Qd,
                                                 const ushort* __restrict__ Kd,
                                                 const ushort* __restrict__ Vd,
                                                 ushort* __restrict__ att) {
    __shared__ union {
        struct { ushort Kb[2][2048]; ushort Vb[2][2048]; } s;   // 8 KB + 8 KB
        float Op[64][68];
    } u;
    __shared__ float Lsh[64];
    int nblk = blockIdx.x;
    int bh = nblk & 63, qt = nblk >> 6;
    int b = bh >> 2, head = bh & 3;
    int i0 = qt * 64;
    const ushort* qp = Qd + (size_t)bh * N_ * HD;
    const ushort* kp = Kd + (size_t)bh * N_ * HD;
    const ushort* vp = Vd + (size_t)bh * HD * N_;

    int tid = threadIdx.x;
    int w = tid >> 6, lane = tid & 63;
    int hl = lane >> 5, r32 = lane & 31;

    // staging: wave 0 -> 4 K regions (c), wave 1 -> 4 V regions (kt*2+dt)
    int goff[4];
    #pragma unroll
    for (int p = 0; p < 4; ++p) {
        if (w == 0) goff[p] = r32 * HD + p * 16 + hl * 8;                       // K[j0+r32][p*16+hl*8]
        else        goff[p] = ((p & 1) * 32 + r32) * N_ + (p >> 1) * 16 + hl * 8; // V[dt*32+r32][j0 + kt*16+hl*8]
    }
    const ushort* gsp = (w == 0) ? kp : vp;
    int gstep = (w == 0) ? 32 * HD : 32;

    // per-lane fragment read bases
    const ushort* kbL = &u.s.Kb[0][0] + lane * 8;
    const ushort* vbL = &u.s.Vb[0][0] + lane * 8;

    // Q B-fragments: q_glob = i0 + w*32 + r32
    bf16x8 aQ[4];
    {
        const ushort* qrow = qp + (size_t)(i0 + w * 32 + r32) * HD;
        #pragma unroll
        for (int c = 0; c < 4; ++c)
            aQ[c] = *(const bf16x8*)(qrow + c * 16 + hl * 8);
    }

    float l = 0.f;
    f32x16 oacc[2];
    #pragma unroll
    for (int dt = 0; dt < 2; ++dt)
        #pragma unroll
        for (int i = 0; i < 16; ++i) oacc[dt][i] = 0.f;

    // prologue: stage tile 0 -> buf 0
    {
        ushort* db = (w == 0) ? &u.s.Kb[0][0] : &u.s.Vb[0][0];
        #pragma unroll
        for (int p = 0; p < 4; ++p)
            GLOAD16(gsp + goff[p], db + p * 512);
    }
    __syncthreads();

    auto body = [&](int cb, int it) {
        if (it < 31) {   // async prefetch next tile into the other buffer
            const ushort* gsi = gsp + (it + 1) * gstep;
            ushort* db = (w == 0) ? &u.s.Kb[cb ^ 1][0] : &u.s.Vb[cb ^ 1][0];
            #pragma unroll
            for (int p = 0; p < 4; ++p)
                GLOAD16(gsi + goff[p], db + p * 512);
        }

        // ---- QK^T swapped (32x32x16): S^T[k = (i&3)+8(i>>2)+4hl][q = r32] ----
        f32x16 sacc;
        #pragma unroll
        for (int i = 0; i < 16; ++i) sacc[i] = 0.f;
        __builtin_amdgcn_s_setprio(1);
        #pragma unroll
        for (int c = 0; c < 4; ++c) {
            bf16x8 aK = *(const bf16x8*)(kbL + cb * 2048 + c * 512);
            sacc = __builtin_amdgcn_mfma_f32_32x32x16_bf16(aK, aQ[c], sacc, 0, 0, 0);
        }
        __builtin_amdgcn_s_setprio(0);

        // ---- no-max softmax: P = exp2(S) ----
        float p0[16];
        #pragma unroll
        for (int i = 0; i < 16; ++i) p0[i] = fexp2(sacc[i]);
        float s4a = (p0[0] + p0[4]) + (p0[8] + p0[12]);
        float s4b = (p0[1] + p0[5]) + (p0[9] + p0[13]);
        float s4c = (p0[2] + p0[6]) + (p0[10] + p0[14]);
        float s4d = (p0[3] + p0[7]) + (p0[11] + p0[15]);
        float sum = (s4a + s4b) + (s4c + s4d);
        sum = sumhalves(sum);
        l += sum;

        // ---- pack P; permlane32_swap pair-exchange -> A-fragments ----
        unsigned pk[4][2];
        #pragma unroll
        for (int R = 0; R < 4; ++R) {
            pk[R][0] = cvtpk(p0[R * 4 + 0], p0[R * 4 + 1]);
            pk[R][1] = cvtpk(p0[R * 4 + 2], p0[R * 4 + 3]);
        }
        unsigned apk[2][4];    // [kt][delta]: k = 16kt + 8hl + 2delta
        #pragma unroll
        for (int kt = 0; kt < 2; ++kt) {
            unsigned w0 = pk[2 * kt][0], w1 = pk[2 * kt][1];
            unsigned w2 = pk[2 * kt + 1][0], w3 = pk[2 * kt + 1][1];
            plswap_pair(w0, w2);
            plswap_pair(w1, w3);
            apk[kt][0] = w0; apk[kt][1] = w1;
            apk[kt][2] = w2; apk[kt][3] = w3;
        }

        // ---- PV (32x32x16) ----
        __builtin_amdgcn_s_setprio(1);
        #pragma unroll
        for (int kt = 0; kt < 2; ++kt) {
            union { unsigned uu[4]; bf16x8 v; } ap;
            ap.uu[0] = apk[kt][0]; ap.uu[1] = apk[kt][1];
            ap.uu[2] = apk[kt][2]; ap.uu[3] = apk[kt][3];
            #pragma unroll
            for (int dt = 0; dt < 2; ++dt) {
                bf16x8 bV = *(const bf16x8*)(vbL + cb * 2048 + (kt * 2 + dt) * 512);
                oacc[dt] = __builtin_amdgcn_mfma_f32_32x32x16_bf16(ap.v, bV, oacc[dt], 0, 0, 0);
            }
        }
        __builtin_amdgcn_s_setprio(0);

        __syncthreads();   // drains prefetch vmcnt + all waves done with buf[cb]
    };

    #pragma unroll 1
    for (int ii = 0; ii < 16; ++ii) {
        body(0, 2 * ii);
        body(1, 2 * ii + 1);
    }

    // ---- epilogue: raw O -> LDS transpose, normalize on store ----
    if (hl == 0) Lsh[w * 32 + r32] = 1.f / l;
    #pragma unroll
    for (int dt = 0; dt < 2; ++dt)
        #pragma unroll
        for (int reg = 0; reg < 16; ++reg)
            u.Op[w * 32 + (reg & 3) + 8 * (reg >> 2) + 4 * hl][dt * 32 + r32] = oacc[dt][reg];
    __syncthreads();

    #pragma unroll
    for (int it = 0; it < 4; ++it) {
        int t = it * 128 + tid;
        int r = t >> 3, c = t & 7;
        float linv = Lsh[r];
        f32x4 v0 = *(const f32x4*)&u.Op[r][c * 8];
        f32x4 v1 = *(const f32x4*)&u.Op[r][c * 8 + 4];
        union { unsigned uu[4]; us8 v; } ov;
        ov.uu[0] = cvtpk(v0[0] * linv, v0[1] * linv);
        ov.uu[1] = cvtpk(v0[2] * linv, v0[3] * linv);
        ov.uu[2] = cvtpk(v1[0] * linv, v1[1] * linv);
        ov.uu[3] = cvtpk(v1[2] * linv, v1[3] * linv);
        *(us8*)(att + ((size_t)b * N_ + i0 + r) * C_ + head * HD + c * 8) = ov.v;
    }
}

// ---------------- Kernel 4: proj GEMM (bf16 MFMA) + bias + residual ----------------
__global__ __launch_bounds__(256) void proj_gemm(const ushort* __restrict__ wp,
                                                 const ushort* __restrict__ att,
                                                 const float* __restrict__ bias,
                                                 const float* __restrict__ x,
                                                 float* __restrict__ out) {
    __shared__ struct { ushort As[64][72]; ushort Bs[128][72]; } s;
    int b = blockIdx.z, m0 = blockIdx.y * 64, n0 = blockIdx.x * 128;
    const ushort* Bsrc = att + (size_t)b * N_ * C_;
    int tid = threadIdx.x;
    int w = tid >> 6, lane = tid & 63;
    int g = lane >> 4, r16 = lane & 15;
    int wm = w >> 1, wn = w & 1;

    f32x4 acc[2][4];
    #pragma unroll
    for (int mf = 0; mf < 2; ++mf)
        #pragma unroll
        for (int nf = 0; nf < 4; ++nf) acc[mf][nf] = (f32x4){0.f, 0.f, 0.f, 0.f};

    for (int k0 = 0; k0 < 256; k0 += 64) {
        __syncthreads();
        #pragma unroll
        for (int it = 0; it < 2; ++it) {
            int t = it * 256 + tid, r = t >> 3, c = t & 7;
            *(us8*)&s.As[r][c * 8] = *(const us8*)(wp + (size_t)(m0 + r) * 256 + k0 + c * 8);
        }
        #pragma unroll
        for (int it = 0; it < 4; ++it) {
            int t = it * 256 + tid, r = t >> 3, c = t & 7;
            *(us8*)&s.Bs[r][c * 8] = *(const us8*)(Bsrc + (size_t)(n0 + r) * 256 + k0 + c * 8);
        }
        __syncthreads();
        bf16x8 aA[2][2], bB[4][2];
        #pragma unroll
        for (int mf = 0; mf < 2; ++mf)
            #pragma unroll
            for (int ks = 0; ks < 2; ++ks)
                aA[mf][ks] = *(const bf16x8*)&s.As[wm * 32 + mf * 16 + r16][ks * 32 + g * 8];
        #pragma unroll
        for (int nf = 0; nf < 4; ++nf)
            #pragma unroll
            for (int ks = 0; ks < 2; ++ks)
                bB[nf][ks] = *(const bf16x8*)&s.Bs[wn * 64 + nf * 16 + r16][ks * 32 + g * 8];
        #pragma unroll
        for (int ks = 0; ks < 2; ++ks)
            #pragma unroll
            for (int mf = 0; mf < 2; ++mf)
                #pragma unroll
                for (int nf = 0; nf < 4; ++nf)
                    acc[mf][nf] = __builtin_amdgcn_mfma_f32_16x16x32_bf16(aA[mf][ks], bB[nf][ks], acc[mf][nf], 0, 0, 0);
    }

    #pragma unroll
    for (int mf = 0; mf < 2; ++mf) {
        #pragma unroll
        for (int reg = 0; reg < 4; ++reg) {
            int c_ = m0 + wm * 32 + mf * 16 + g * 4 + reg;
            float bi = bias[c_];
            #pragma unroll
            for (int nf = 0; nf < 4; ++nf) {
                int n = n0 + wn * 64 + nf * 16 + r16;
                size_t o = ((size_t)b * C_ + c_) * N_ + n;
                out[o] = acc[mf][nf][reg] + bi + x[o];
            }
        }
    }
}

extern "C" void kernel_launch(void* const* d_in, const int* in_sizes, int n_in,
                              void* d_out, int out_size, void* d_ws, size_t ws_size,
                              hipStream_t stream) {
    const float* x      = (const float*)d_in[0];
    const float* gn_w   = (const float*)d_in[1];
    const float* gn_b   = (const float*)d_in[2];
    const float* qkv_w  = (const float*)d_in[3];
    const float* qkv_b  = (const float*)d_in[4];
    const float* proj_w = (const float*)d_in[5];
    const float* proj_b = (const float*)d_in[6];
    float* out = (float*)d_out;

    char* ws = (char*)d_ws;
    ushort* wq_bf = (ushort*)(ws);                               // 384 KB
    ushort* wp_bf = (ushort*)(ws + 393216);                      // 128 KB
    ushort* xnt   = (ushort*)(ws + (1u << 20));                  // 8 MB  [b][n][c]
    ushort* Qd    = (ushort*)(ws + (size_t)16 * 1024 * 1024);    // 8 MB  [b][h][n][d]
    ushort* Kd    = (ushort*)(ws + (size_t)24 * 1024 * 1024);    // 8 MB  [b][h][n][d]
    ushort* Vd    = (ushort*)(ws + (size_t)32 * 1024 * 1024);    // 8 MB  [b][h][d][n]
    ushort* att_t = (ushort*)(ws + (size_t)40 * 1024 * 1024);    // 8 MB  [b][n][c]

    prep_w<<<dim3(256), dim3(256), 0, stream>>>(qkv_w, proj_w, wq_bf, wp_bf);
    gn_kernel<<<dim3(B_ * 16), dim3(256), 0, stream>>>(x, gn_w, gn_b, xnt);
    qkv_gemm<<<dim3(8, 12, B_), dim3(256), 0, stream>>>(wq_bf, xnt, qkv_b, Qd, Kd, Vd);
    attn_mfma<<<dim3(1024), dim3(128), 0, stream>>>(Qd, Kd, Vd, att_t);
    proj_gemm<<<dim3(8, 4, B_), dim3(256), 0, stream>>>(wp_bf, att_t, proj_b, x, out);
}